// Round 8
// baseline (632.444 us; speedup 1.0000x reference)
//
#include <hip/hip_runtime.h>
#include <hip/hip_fp16.h>

#define NN 100000
#define EC 6400000
#define ED 400000
#define BN_EPS 1e-5f
#define NB 391               // node buckets of 256
#define CAPC 18432           // per-bucket padded capacity, eic
#define CAPD 2048            // per-bucket padded capacity, eid
#define EPB 8192             // edges per scatter block
#define NBK_C 782            // ceil(EC/EPB)
#define NBK_D 49             // ceil(ED/EPB)
#define PREPB 16             // x/W prep blocks appended to scatter grid
#define TIL 6250             // src-tile rows (16 tiles x 6250 = NN)

// ---------------- R16 prep (proven): fixed-capacity buckets + sorted scatter --

__global__ __launch_bounds__(1024)
void zero_small(int* __restrict__ cnt_c, int* __restrict__ cnt_d,
                float* __restrict__ stats) {
    int t = threadIdx.x;
    for (int i = t; i < NB; i += 1024) { cnt_c[i] = 0; cnt_d[i] = 0; }
    for (int i = t; i < 5 * 256; i += 1024) stats[i] = 0.f;
}

__global__ __launch_bounds__(1024)
void scatter_fused(const int* __restrict__ eic, const int* __restrict__ eid,
                   int* __restrict__ cnt_c, int* __restrict__ cnt_d,
                   unsigned* __restrict__ packed_c, unsigned* __restrict__ packed_d,
                   const float* __restrict__ x, const float* __restrict__ W1l,
                   const float* __restrict__ W1r, float* __restrict__ xp,
                   __half* __restrict__ xp16,
                   float* __restrict__ W1lp, float* __restrict__ W1rp) {
    int blk = blockIdx.x;
    int tid = threadIdx.x;
    if (blk >= NBK_C + NBK_D) {
        int pb = blk - (NBK_C + NBK_D);
        int t = pb * 1024 + tid;
        if (t < 64) {
            int f = t >> 3, k = t & 7;
            W1lp[t] = (k < 5) ? W1l[f * 5 + k] : 0.f;
            W1rp[t] = (k < 5) ? W1r[f * 5 + k] : 0.f;
        }
        for (int idx = t; idx < NN * 8; idx += PREPB * 1024) {
            int f = idx & 7, i = idx >> 3;
            float v = (f < 5) ? x[i * 5 + f] : 0.f;
            xp[idx] = v;
            xp16[idx] = __float2half(v);
        }
        return;
    }
    const int* ei; int E, cap, base; int* cnt; unsigned* packed;
    if (blk < NBK_C) { ei = eic; E = EC; cnt = cnt_c; packed = packed_c; cap = CAPC; base = blk; }
    else             { ei = eid; E = ED; cnt = cnt_d; packed = packed_d; cap = CAPD; base = blk - NBK_C; }

    __shared__ int h[NB];
    __shared__ int lcur[NB];
    __shared__ int dg[NB];
    __shared__ int ws[16];
    __shared__ int sbuf[EPB];
    __shared__ unsigned short sbkt[EPB];

    for (int i = tid; i < NB; i += 1024) h[i] = 0;
    __syncthreads();
    int beg = base * EPB, end = min(E, beg + EPB);
    int ecnt = end - beg;
    for (int e = beg + tid * 4; e < end; e += 4096) {
        int4 d4 = *(const int4*)&ei[E + e];
        atomicAdd(&h[d4.x >> 8], 1);
        atomicAdd(&h[d4.y >> 8], 1);
        atomicAdd(&h[d4.z >> 8], 1);
        atomicAdd(&h[d4.w >> 8], 1);
    }
    __syncthreads();
    {
        int v = (tid < NB) ? h[tid] : 0;
        int lane = tid & 63, w = tid >> 6;
        int xx = v;
        #pragma unroll
        for (int sh = 1; sh < 64; sh <<= 1) { int y = __shfl_up(xx, sh); if (lane >= sh) xx += y; }
        if (lane == 63) ws[w] = xx;
        __syncthreads();
        int wb = 0;
        #pragma unroll
        for (int j = 0; j < 16; ++j) if (j < w) wb += ws[j];
        int excl = wb + xx - v;
        if (tid < NB) {
            lcur[tid] = excl;
            int gb = v ? atomicAdd(&cnt[tid], v) : 0;
            dg[tid] = gb - excl;
        }
    }
    __syncthreads();
    for (int e = beg + tid * 4; e < end; e += 4096) {
        int4 s4 = *(const int4*)&ei[e];
        int4 d4 = *(const int4*)&ei[E + e];
        { int b = d4.x >> 8; int p = atomicAdd(&lcur[b], 1); sbuf[p] = s4.x | ((d4.x & 255) << 17); sbkt[p] = (unsigned short)b; }
        { int b = d4.y >> 8; int p = atomicAdd(&lcur[b], 1); sbuf[p] = s4.y | ((d4.y & 255) << 17); sbkt[p] = (unsigned short)b; }
        { int b = d4.z >> 8; int p = atomicAdd(&lcur[b], 1); sbuf[p] = s4.z | ((d4.z & 255) << 17); sbkt[p] = (unsigned short)b; }
        { int b = d4.w >> 8; int p = atomicAdd(&lcur[b], 1); sbuf[p] = s4.w | ((d4.w & 255) << 17); sbkt[p] = (unsigned short)b; }
    }
    __syncthreads();
    for (int j = tid; j < ecnt; j += 1024) {
        int b = sbkt[j];
        unsigned idx = (unsigned)(dg[b] + j);
        if (idx < (unsigned)cap)
            packed[(size_t)b * cap + idx] = (unsigned)sbuf[j];
    }
}

// ---------------- R17 csr_sort: eic keyed by (dst_local, src_tile) -----------
__global__ __launch_bounds__(1024)
void csr_sort(const unsigned* __restrict__ packed_c, const int* __restrict__ cnt_c,
              int* __restrict__ csr_c, int* __restrict__ offs_c, float* __restrict__ inv_c,
              unsigned short* __restrict__ cnt16,
              const unsigned* __restrict__ packed_d, const int* __restrict__ cnt_d,
              int* __restrict__ csr_d, int* __restrict__ offs_d,
              int* __restrict__ deg_d, float* __restrict__ inv_d) {
    __shared__ int h4[4096];
    __shared__ int ws[16];
    __shared__ int ebuf[CAPC];
    int blk = blockIdx.x, tid = threadIdx.x;
    if (blk < NB) {
        int b = blk;
        size_t ebeg = (size_t)b * CAPC;
        int ecnt = min(cnt_c[b], CAPC);
        int node0 = b << 8;
        for (int i = tid; i < 4096; i += 1024) h4[i] = 0;
        __syncthreads();
        for (int e = tid; e < ecnt; e += 1024) {
            unsigned u = packed_c[ebeg + e];
            int dl = (int)(u >> 17);
            int src = (int)(u & 0x1FFFFu);
            atomicAdd(&h4[(dl << 4) | (src / TIL)], 1);
        }
        __syncthreads();
        int i0 = tid * 4;
        int v0 = h4[i0], v1 = h4[i0 + 1], v2 = h4[i0 + 2], v3 = h4[i0 + 3];
        int s = v0 + v1 + v2 + v3;
        {
            int lane = tid & 63, w = tid >> 6;
            int xx = s;
            #pragma unroll
            for (int sh = 1; sh < 64; sh <<= 1) { int y = __shfl_up(xx, sh); if (lane >= sh) xx += y; }
            if (lane == 63) ws[w] = xx;
            __syncthreads();
            int wb = 0;
            #pragma unroll
            for (int j = 0; j < 16; ++j) if (j < w) wb += ws[j];
            int e0 = wb + xx - s;
            h4[i0] = e0;
            h4[i0 + 1] = e0 + v0;
            h4[i0 + 2] = e0 + v0 + v1;
            h4[i0 + 3] = e0 + v0 + v1 + v2;
        }
        __syncthreads();
        for (int i = tid; i < 4096; i += 1024) {
            int node = node0 + (i >> 4);
            if (node < NN) {
                int st = h4[i];
                int en = (i == 4095) ? ecnt : h4[i + 1];
                cnt16[(size_t)node * 16 + (i & 15)] = (unsigned short)(en - st);
            }
        }
        if (tid < 256) {
            int node = node0 + tid;
            if (node < NN) {
                int st = h4[tid << 4];
                int en = (tid == 255) ? ecnt : h4[(tid + 1) << 4];
                int dgc = en - st;
                offs_c[node] = (int)ebeg + st;
                inv_c[node] = 1.0f / (float)(dgc > 1 ? dgc : 1);
            }
        }
        __syncthreads();
        for (int e = tid; e < ecnt; e += 1024) {
            unsigned u = packed_c[ebeg + e];
            int dl = (int)(u >> 17);
            int src = (int)(u & 0x1FFFFu);
            int p = atomicAdd(&h4[(dl << 4) | (src / TIL)], 1);
            ebuf[p] = src;
        }
        __syncthreads();
        for (int e = tid; e < ecnt; e += 1024) csr_c[ebeg + e] = ebuf[e];
    } else {
        int b = blk - NB;
        int* h = h4;
        int* loff = h4 + 256;
        size_t ebeg = (size_t)b * CAPD;
        int ecnt = min(cnt_d[b], CAPD);
        int node0 = b << 8;
        int nn = min(256, NN - node0);
        if (tid < 256) h[tid] = 0;
        __syncthreads();
        for (int e = tid; e < ecnt; e += 1024)
            atomicAdd(&h[packed_d[ebeg + e] >> 17], 1);
        __syncthreads();
        int v = (tid < 256) ? h[tid] : 0;
        {
            int lane = tid & 63, w = tid >> 6;
            int xx = v;
            #pragma unroll
            for (int sh = 1; sh < 64; sh <<= 1) { int y = __shfl_up(xx, sh); if (lane >= sh) xx += y; }
            if (lane == 63 && w < 4) ws[w] = xx;
            __syncthreads();
            if (tid < 256) {
                int wb = 0;
                #pragma unroll
                for (int j = 0; j < 4; ++j) if (j < w) wb += ws[j];
                int excl = wb + xx - v;
                loff[tid] = excl;
                if (tid < nn) {
                    int node = node0 + tid;
                    offs_d[node] = (int)ebeg + excl;
                    deg_d[node] = v;
                    inv_d[node] = 1.0f / (float)(v > 1 ? v : 1);
                }
            }
        }
        __syncthreads();
        for (int e = tid; e < ecnt; e += 1024) {
            unsigned u = packed_d[ebeg + e];
            int p = atomicAdd(&loff[u >> 17], 1);
            ebuf[p] = (int)(u & 0x1FFFFu);
        }
        __syncthreads();
        for (int e = tid; e < ecnt; e += 1024) csr_d[ebeg + e] = ebuf[e];
    }
}

// ---------------- R17 sage_tiled: src-tile LDS-staged aggregation (eic) ------
template<bool APPLY_BN>
__global__ __launch_bounds__(512)
void sage_tiled(const float* __restrict__ hin, const __half* __restrict__ hin16,
                const float* __restrict__ stats_in,
                const float* __restrict__ gin, const float* __restrict__ bin,
                const int* __restrict__ offs, const unsigned short* __restrict__ cnt16,
                const int* __restrict__ csr, const float* __restrict__ inv,
                const float* __restrict__ Wl, const float* __restrict__ Wr,
                float* __restrict__ hout, __half* __restrict__ hout16,
                float* __restrict__ stats_out) {
    __shared__ uint4 tile[TIL];           // 100 KB
    __shared__ float wl[64], wr[64];
    __shared__ float bl[16];
    int tid = threadIdx.x;
    if (tid < 64) { wl[tid] = Wl[tid]; wr[tid] = Wr[tid]; }
    if (tid < 16) bl[tid] = 0.f;
    int n = blockIdx.x * 512 + tid;
    bool ok = (n < NN);
    int nc = ok ? n : NN - 1;
    int cur = offs[nc];
    float im = inv[nc];
    const uint4* c16 = (const uint4*)(cnt16 + (size_t)nc * 16);
    uint4 ca = c16[0], cb = c16[1];
    unsigned cw[8] = { ca.x, ca.y, ca.z, ca.w, cb.x, cb.y, cb.z, cb.w };

    float a0 = 0, a1 = 0, a2 = 0, a3 = 0, a4 = 0, a5 = 0, a6 = 0, a7 = 0;
    int dsum = 0;
    #pragma unroll
    for (int t = 0; t < 16; ++t) {
        __syncthreads();
        const uint4* sp = (const uint4*)hin16 + t * TIL;
        for (int r = tid; r < TIL; r += 512) tile[r] = sp[r];
        __syncthreads();
        unsigned wv = cw[t >> 1];
        int c = (t & 1) ? (int)(wv >> 16) : (int)(wv & 0xFFFFu);
        if (!ok) c = 0;
        dsum += c;
        int base = t * TIL;
        for (int k = 0; k < c; ++k) {                   // divergent, no barrier
            int u = csr[cur++];
            uint4 rv = tile[u - base];
            float2 p0 = __half22float2(*(const __half2*)&rv.x);
            float2 p1 = __half22float2(*(const __half2*)&rv.y);
            float2 p2 = __half22float2(*(const __half2*)&rv.z);
            float2 p3 = __half22float2(*(const __half2*)&rv.w);
            a0 += p0.x; a1 += p0.y; a2 += p1.x; a3 += p1.y;
            a4 += p2.x; a5 += p2.y; a6 += p3.x; a7 += p3.y;
        }
    }

    float ac[8] = { a0, a1, a2, a3, a4, a5, a6, a7 };
    float dnz = (dsum > 0) ? 1.f : 0.f;
    const float4* hp = (const float4*)(hin + (size_t)nc * 8);
    float4 h0 = hp[0], h1 = hp[1];
    float hk[8] = { h0.x, h0.y, h0.z, h0.w, h1.x, h1.y, h1.z, h1.w };
    float ag[8], hh[8];
    #pragma unroll
    for (int k = 0; k < 8; ++k) {
        float sck = 1.f, shk = 0.f;
        if constexpr (APPLY_BN) {
            float m = stats_in[k * 16] * (1.f / NN);
            float v = stats_in[(8 + k) * 16] * (1.f / NN) - m * m;
            float is = rsqrtf(v + BN_EPS);
            sck = gin[k] * is;
            shk = bin[k] - m * sck;
        }
        ag[k] = fmaf(sck, ac[k] * im, shk * dnz);
        hh[k] = fmaf(sck, hk[k], shk);
    }
    float y[8];
    #pragma unroll
    for (int f = 0; f < 8; ++f) y[f] = 0.f;
    #pragma unroll
    for (int k = 0; k < 8; ++k) {
        #pragma unroll
        for (int f = 0; f < 8; ++f) {
            y[f] = fmaf(ag[k], wl[f * 8 + k], y[f]);
            y[f] = fmaf(hh[k], wr[f * 8 + k], y[f]);
        }
    }
    float n2 = 0.f;
    #pragma unroll
    for (int f = 0; f < 8; ++f) n2 += y[f] * y[f];
    float rn = 1.0f / fmaxf(sqrtf(n2), 1e-12f);
    float r[8];
    #pragma unroll
    for (int f = 0; f < 8; ++f) {
        float z = fmaxf(y[f] * rn, 0.f);
        r[f] = ok ? z : 0.f;
    }
    if (ok) {
        float4 o0 = { r[0], r[1], r[2], r[3] };
        float4 o1 = { r[4], r[5], r[6], r[7] };
        ((float4*)(hout + (size_t)n * 8))[0] = o0;
        ((float4*)(hout + (size_t)n * 8))[1] = o1;
        __half2 q0 = __floats2half2_rn(r[0], r[1]);
        __half2 q1 = __floats2half2_rn(r[2], r[3]);
        __half2 q2 = __floats2half2_rn(r[4], r[5]);
        __half2 q3 = __floats2half2_rn(r[6], r[7]);
        uint4 ov = { *(unsigned*)&q0, *(unsigned*)&q1, *(unsigned*)&q2, *(unsigned*)&q3 };
        *(uint4*)(hout16 + (size_t)n * 8) = ov;
    }
    float r2[8];
    #pragma unroll
    for (int f = 0; f < 8; ++f) r2[f] = r[f] * r[f];
    #pragma unroll
    for (int m = 1; m < 64; m <<= 1) {
        #pragma unroll
        for (int f = 0; f < 8; ++f) {
            r[f] += __shfl_xor(r[f], m);
            r2[f] += __shfl_xor(r2[f], m);
        }
    }
    if ((tid & 63) == 0) {
        #pragma unroll
        for (int f = 0; f < 8; ++f) {
            atomicAdd(&bl[f], r[f]);
            atomicAdd(&bl[8 + f], r2[f]);
        }
    }
    __syncthreads();
    if (tid < 16) atomicAdd(&stats_out[tid * 16], bl[tid]);
}

// ---------------- fused SAGE layer v7 (FROZEN; eid layer only) ---------------
#define ACC8(RV, M) do { \
    float2 q0 = __half22float2(*(const __half2*)&RV.x); \
    float2 q1 = __half22float2(*(const __half2*)&RV.y); \
    float2 q2 = __half22float2(*(const __half2*)&RV.z); \
    float2 q3 = __half22float2(*(const __half2*)&RV.w); \
    a0 = fmaf(q0.x, M, a0); a1 = fmaf(q0.y, M, a1); \
    a2 = fmaf(q1.x, M, a2); a3 = fmaf(q1.y, M, a3); \
    a4 = fmaf(q2.x, M, a4); a5 = fmaf(q2.y, M, a5); \
    a6 = fmaf(q3.x, M, a6); a7 = fmaf(q3.y, M, a7); \
} while (0)

template<bool APPLY_BN>
__global__ __launch_bounds__(256)
void sage_layer8(const float* __restrict__ hin,
                 const __half* __restrict__ hin16,
                 const float* __restrict__ stats_in,
                 const float* __restrict__ gin, const float* __restrict__ bin,
                 const int* __restrict__ offs, const int* __restrict__ deg,
                 const int* __restrict__ csr, const float* __restrict__ inv,
                 const float* __restrict__ Wl, const float* __restrict__ Wr,
                 float* __restrict__ hout, __half* __restrict__ hout16,
                 float* __restrict__ stats_out) {
    __shared__ float bl[16];
    int tid = threadIdx.x;
    if (tid < 16) bl[tid] = 0.f;
    __syncthreads();
    int wave = tid >> 6, lane = tid & 63, g = lane >> 3, f = lane & 7;

    float wls[8], wrs[8];
    float Bl = 0.f, Br = 0.f;
    #pragma unroll
    for (int k = 0; k < 8; ++k) {
        float w_l = Wl[f * 8 + k], w_r = Wr[f * 8 + k];
        float sck = 1.f, shk = 0.f;
        if constexpr (APPLY_BN) {
            float m = stats_in[k * 16] * (1.f / NN);
            float v = stats_in[(8 + k) * 16] * (1.f / NN) - m * m;
            float is = rsqrtf(v + BN_EPS);
            sck = gin[k] * is;
            shk = bin[k] - m * sck;
        }
        wls[k] = sck * w_l;
        wrs[k] = sck * w_r;
        Bl = fmaf(shk, w_l, Bl);
        Br = fmaf(shk, w_r, Br);
    }

    float acc_r = 0.f, acc_r2 = 0.f;
    const int stride = gridDim.x * 32;
    for (int i0 = (blockIdx.x * 4 + wave) * 8; i0 < NN; i0 += stride) {
        int i = i0 + g;
        int ic = min(i, NN - 1);
        bool ok = (i < NN);
        int d = ok ? deg[ic] : 0;
        int o = offs[ic];
        float im = inv[ic];
        const float4* hp = (const float4*)(hin + (size_t)ic * 8);
        float4 h0 = hp[0];
        float4 h1 = hp[1];
        float a0 = 0, a1 = 0, a2 = 0, a3 = 0, a4 = 0, a5 = 0, a6 = 0, a7 = 0;
        for (int b = 0; b < d; b += 32) {
            int e = b + f * 4;
            const int* cp = csr + o + e;
            int c0 = cp[0], c1 = cp[1], c2 = cp[2], c3 = cp[3];
            bool k0 = (e < d), k1 = (e + 1 < d), k2 = (e + 2 < d), k3 = (e + 3 < d);
            unsigned s0 = k0 ? ((unsigned)c0 & 0x1FFFFu) : 0u;
            unsigned s1 = k1 ? ((unsigned)c1 & 0x1FFFFu) : 0u;
            unsigned s2 = k2 ? ((unsigned)c2 & 0x1FFFFu) : 0u;
            unsigned s3 = k3 ? ((unsigned)c3 & 0x1FFFFu) : 0u;
            uint4 r0 = *(const uint4*)(hin16 + (size_t)s0 * 8);
            uint4 r1 = *(const uint4*)(hin16 + (size_t)s1 * 8);
            uint4 r2 = *(const uint4*)(hin16 + (size_t)s2 * 8);
            uint4 r3 = *(const uint4*)(hin16 + (size_t)s3 * 8);
            float m0 = k0 ? 1.f : 0.f;
            float m1 = k1 ? 1.f : 0.f;
            float m2 = k2 ? 1.f : 0.f;
            float m3 = k3 ? 1.f : 0.f;
            ACC8(r0, m0);
            ACC8(r1, m1);
            ACC8(r2, m2);
            ACC8(r3, m3);
        }
        #pragma unroll
        for (int msk = 1; msk < 8; msk <<= 1) {
            a0 += __shfl_xor(a0, msk); a1 += __shfl_xor(a1, msk);
            a2 += __shfl_xor(a2, msk); a3 += __shfl_xor(a3, msk);
            a4 += __shfl_xor(a4, msk); a5 += __shfl_xor(a5, msk);
            a6 += __shfl_xor(a6, msk); a7 += __shfl_xor(a7, msk);
        }
        float dnz = (d > 0) ? 1.f : 0.f;
        float hk[8] = { h0.x, h0.y, h0.z, h0.w, h1.x, h1.y, h1.z, h1.w };
        float acv[8] = { a0, a1, a2, a3, a4, a5, a6, a7 };
        float y = fmaf(dnz, Bl, Br);
        #pragma unroll
        for (int k = 0; k < 8; ++k) {
            y = fmaf(acv[k] * im, wls[k], y);
            y = fmaf(hk[k], wrs[k], y);
        }
        float n2 = y * y;
        n2 += __shfl_xor(n2, 1);
        n2 += __shfl_xor(n2, 2);
        n2 += __shfl_xor(n2, 4);
        float z = y / fmaxf(sqrtf(n2), 1e-12f);
        float r = fmaxf(z, 0.f);
        r = ok ? r : 0.f;
        if (ok) {
            hout[(size_t)i * 8 + f] = r;
            hout16[(size_t)i * 8 + f] = __float2half(r);
        }
        acc_r += r;
        acc_r2 += r * r;
    }
    atomicAdd(&bl[f], acc_r);
    atomicAdd(&bl[8 + f], acc_r2);
    __syncthreads();
    if (tid < 16) atomicAdd(&stats_out[tid * 16], bl[tid]);
}

__global__ void apply_bn_out(const float* __restrict__ hin,
                             const float* __restrict__ stats,
                             const float* __restrict__ g, const float* __restrict__ b,
                             float* __restrict__ out) {
    int t = blockIdx.x * blockDim.x + threadIdx.x;
    if (t >= NN * 8) return;
    int f = t & 7;
    float m = stats[f * 16] * (1.0f / NN);
    float v = stats[(8 + f) * 16] * (1.0f / NN) - m * m;
    float sc = g[f] * rsqrtf(v + BN_EPS);
    float sh = b[f] - m * sc;
    out[t] = fmaf(hin[t], sc, sh);
}

// ---------------- launch ----------------

static inline char* bump(char*& p, size_t bytes) {
    char* r = p;
    p += (bytes + 255) & ~(size_t)255;
    return r;
}

extern "C" void kernel_launch(void* const* d_in, const int* in_sizes, int n_in,
                              void* d_out, int out_size, void* d_ws, size_t ws_size,
                              hipStream_t stream) {
    const float* x   = (const float*)d_in[0];
    const int* eic   = (const int*)d_in[1];
    const int* eid   = (const int*)d_in[2];
    const float* W1l = (const float*)d_in[3];
    const float* W1r = (const float*)d_in[4];
    const float* W2l = (const float*)d_in[5];
    const float* W2r = (const float*)d_in[6];
    const float* W3l = (const float*)d_in[7];
    const float* W3r = (const float*)d_in[8];
    const float* W4l = (const float*)d_in[9];
    const float* W4r = (const float*)d_in[10];
    const float* g1 = (const float*)d_in[11];
    const float* b1 = (const float*)d_in[12];
    const float* g2 = (const float*)d_in[13];
    const float* b2 = (const float*)d_in[14];
    const float* g3 = (const float*)d_in[15];
    const float* b3 = (const float*)d_in[16];
    const float* g4 = (const float*)d_in[17];
    const float* b4 = (const float*)d_in[18];
    float* out = (float*)d_out;

    char* p = (char*)d_ws;
    float* stats   = (float*)bump(p, 5 * 256 * 4);
    int*   cnt_c   = (int*)  bump(p, NB * 4);
    int*   cnt_d   = (int*)  bump(p, NB * 4);
    int*   offs_c  = (int*)  bump(p, NN * 4);
    float* inv_c   = (float*)bump(p, NN * 4);
    int*   offs_d  = (int*)  bump(p, NN * 4);
    int*   deg_d   = (int*)  bump(p, NN * 4);
    float* inv_d   = (float*)bump(p, NN * 4);
    unsigned short* cnt16 = (unsigned short*)bump(p, (size_t)NN * 16 * 2);
    int*   csr_c   = (int*)  bump(p, ((size_t)NB * CAPC + 256) * 4);
    int*   csr_d   = (int*)  bump(p, ((size_t)NB * CAPD + 256) * 4);
    float* xp32    = (float*)bump(p, (size_t)NN * 8 * 4);
    __half* xp16   = (__half*)bump(p, (size_t)NN * 8 * 2);
    float* W1lp    = (float*)bump(p, 64 * 4);
    float* W1rp    = (float*)bump(p, 64 * 4);
    unsigned* packed_d = (unsigned*)bump(p, (size_t)NB * CAPD * 4);
    // packed_c dead after csr_sort; overlay activation ping-pong (f32 + fp16)
    char* pc = p;
    unsigned* packed_c = (unsigned*)bump(p, (size_t)NB * CAPC * 4);
    char* pr = pc;
    float*  r_a   = (float*) bump(pr, (size_t)NN * 8 * 4);
    float*  r_b   = (float*) bump(pr, (size_t)NN * 8 * 4);
    __half* h16_a = (__half*)bump(pr, (size_t)NN * 8 * 2);
    __half* h16_b = (__half*)bump(pr, (size_t)NN * 8 * 2);
    (void)ws_size; (void)in_sizes; (void)n_in; (void)out_size;

    // 9 dispatches total
    zero_small<<<1, 1024, 0, stream>>>(cnt_c, cnt_d, stats);
    scatter_fused<<<NBK_C + NBK_D + PREPB, 1024, 0, stream>>>(
        eic, eid, cnt_c, cnt_d, packed_c, packed_d,
        x, W1l, W1r, xp32, xp16, W1lp, W1rp);
    csr_sort<<<2 * NB, 1024, 0, stream>>>(
        packed_c, cnt_c, csr_c, offs_c, inv_c, cnt16,
        packed_d, cnt_d, csr_d, offs_d, deg_d, inv_d);

    const int TB = 196;   // ceil(NN/512) blocks, thread = node
    sage_tiled<false><<<TB, 512, 0, stream>>>(
        xp32, xp16, nullptr, nullptr, nullptr,
        offs_c, cnt16, csr_c, inv_c, W1lp, W1rp, r_a, h16_a, stats + 0);
    sage_tiled<true><<<TB, 512, 0, stream>>>(
        r_a, h16_a, stats + 0, g1, b1,
        offs_c, cnt16, csr_c, inv_c, W4l, W4r, r_b, h16_b, stats + 256);
    sage_layer8<true><<<2048, 256, 0, stream>>>(
        r_b, h16_b, stats + 256, g2, b2,
        offs_d, deg_d, csr_d, inv_d, W2l, W2r, r_a, h16_a, stats + 512);
    sage_tiled<true><<<TB, 512, 0, stream>>>(
        r_a, h16_a, stats + 512, g3, b3,
        offs_c, cnt16, csr_c, inv_c, W3l, W3r, r_b, h16_b, stats + 768);
    sage_tiled<true><<<TB, 512, 0, stream>>>(
        r_b, h16_b, stats + 768, g4, b4,
        offs_c, cnt16, csr_c, inv_c, W3l, W3r, r_a, h16_a, stats + 1024);
    apply_bn_out<<<(NN * 8 + 255) / 256, 256, 0, stream>>>(r_a, stats + 1024, g4, b4, out);
}

// Round 9
// 525.920 us; speedup vs baseline: 1.2025x; 1.2025x over previous
//
#include <hip/hip_runtime.h>
#include <hip/hip_fp16.h>

#define NN 100000
#define EC 6400000
#define ED 400000
#define BN_EPS 1e-5f
#define NB 391               // node buckets of 256
#define CAPC 18432           // per-bucket padded capacity, eic (mean 16384 + 16sd)
#define CAPD 2048            // per-bucket padded capacity, eid (mean 1023 + 32sd)
#define EPB 8192             // edges per scatter block
#define NBK_C 782            // ceil(EC/EPB)
#define NBK_D 49             // ceil(ED/EPB)
#define PREPB 16             // x/W prep blocks appended to scatter grid

// ---------------- R18 prep: R16 sorted scatter, dst kept in regs --------------
// R6-proven structure. Change: pass-2 no longer re-reads dst from global; the
// two int4 dst groups (EPB/4/1024 == 2 per thread) stay live in registers
// across the scan. Saves 25.6 MB (one full strided pass), no LDS/occupancy
// change. Sage kernels are FROZEN (R2/R8 redesigns both lost to the per-CU
// random-request wall: ~7 cyc/line, 25k req/CU -> ~73 us/eic layer floor).

__global__ __launch_bounds__(1024)
void zero_small(int* __restrict__ cnt_c, int* __restrict__ cnt_d,
                float* __restrict__ stats) {
    int t = threadIdx.x;
    for (int i = t; i < NB; i += 1024) { cnt_c[i] = 0; cnt_d[i] = 0; }
    for (int i = t; i < 5 * 256; i += 1024) stats[i] = 0.f;
}

__global__ __launch_bounds__(1024)
void scatter_fused(const int* __restrict__ eic, const int* __restrict__ eid,
                   int* __restrict__ cnt_c, int* __restrict__ cnt_d,
                   unsigned* __restrict__ packed_c, unsigned* __restrict__ packed_d,
                   const float* __restrict__ x, const float* __restrict__ W1l,
                   const float* __restrict__ W1r, float* __restrict__ xp,
                   __half* __restrict__ xp16,
                   float* __restrict__ W1lp, float* __restrict__ W1rp) {
    int blk = blockIdx.x;
    int tid = threadIdx.x;
    if (blk >= NBK_C + NBK_D) {
        int pb = blk - (NBK_C + NBK_D);
        int t = pb * 1024 + tid;
        if (t < 64) {
            int f = t >> 3, k = t & 7;
            W1lp[t] = (k < 5) ? W1l[f * 5 + k] : 0.f;
            W1rp[t] = (k < 5) ? W1r[f * 5 + k] : 0.f;
        }
        for (int idx = t; idx < NN * 8; idx += PREPB * 1024) {
            int f = idx & 7, i = idx >> 3;
            float v = (f < 5) ? x[i * 5 + f] : 0.f;
            xp[idx] = v;
            xp16[idx] = __float2half(v);
        }
        return;
    }
    const int* ei; int E, cap, base; int* cnt; unsigned* packed;
    if (blk < NBK_C) { ei = eic; E = EC; cnt = cnt_c; packed = packed_c; cap = CAPC; base = blk; }
    else             { ei = eid; E = ED; cnt = cnt_d; packed = packed_d; cap = CAPD; base = blk - NBK_C; }

    __shared__ int h[NB];
    __shared__ int lcur[NB];
    __shared__ int dg[NB];
    __shared__ int ws[16];
    __shared__ int sbuf[EPB];
    __shared__ unsigned short sbkt[EPB];

    for (int i = tid; i < NB; i += 1024) h[i] = 0;
    __syncthreads();
    int beg = base * EPB, end = min(E, beg + EPB);
    int ecnt = end - beg;
    // pass 1: LDS bucket histogram; dst values stay in d4a/d4b registers
    int e0 = beg + tid * 4;
    int e1 = e0 + 4096;
    bool v0 = (e0 < end), v1 = (e1 < end);
    int4 d4a = {0, 0, 0, 0}, d4b = {0, 0, 0, 0};
    if (v0) {
        d4a = *(const int4*)&ei[E + e0];
        atomicAdd(&h[d4a.x >> 8], 1);
        atomicAdd(&h[d4a.y >> 8], 1);
        atomicAdd(&h[d4a.z >> 8], 1);
        atomicAdd(&h[d4a.w >> 8], 1);
    }
    if (v1) {
        d4b = *(const int4*)&ei[E + e1];
        atomicAdd(&h[d4b.x >> 8], 1);
        atomicAdd(&h[d4b.y >> 8], 1);
        atomicAdd(&h[d4b.z >> 8], 1);
        atomicAdd(&h[d4b.w >> 8], 1);
    }
    __syncthreads();
    // block-local exclusive scan of h + ONE global reserve per (block,bucket)
    {
        int v = (tid < NB) ? h[tid] : 0;
        int lane = tid & 63, w = tid >> 6;
        int xx = v;
        #pragma unroll
        for (int sh = 1; sh < 64; sh <<= 1) { int y = __shfl_up(xx, sh); if (lane >= sh) xx += y; }
        if (lane == 63) ws[w] = xx;
        __syncthreads();
        int wb = 0;
        #pragma unroll
        for (int j = 0; j < 16; ++j) if (j < w) wb += ws[j];
        int excl = wb + xx - v;
        if (tid < NB) {
            lcur[tid] = excl;
            int gb = v ? atomicAdd(&cnt[tid], v) : 0;
            dg[tid] = gb - excl;
        }
    }
    __syncthreads();
    // pass 2: counting-sort into LDS (src from global, dst from registers)
    if (v0) {
        int4 s4 = *(const int4*)&ei[e0];
        { int b = d4a.x >> 8; int p = atomicAdd(&lcur[b], 1); sbuf[p] = s4.x | ((d4a.x & 255) << 17); sbkt[p] = (unsigned short)b; }
        { int b = d4a.y >> 8; int p = atomicAdd(&lcur[b], 1); sbuf[p] = s4.y | ((d4a.y & 255) << 17); sbkt[p] = (unsigned short)b; }
        { int b = d4a.z >> 8; int p = atomicAdd(&lcur[b], 1); sbuf[p] = s4.z | ((d4a.z & 255) << 17); sbkt[p] = (unsigned short)b; }
        { int b = d4a.w >> 8; int p = atomicAdd(&lcur[b], 1); sbuf[p] = s4.w | ((d4a.w & 255) << 17); sbkt[p] = (unsigned short)b; }
    }
    if (v1) {
        int4 s4 = *(const int4*)&ei[e1];
        { int b = d4b.x >> 8; int p = atomicAdd(&lcur[b], 1); sbuf[p] = s4.x | ((d4b.x & 255) << 17); sbkt[p] = (unsigned short)b; }
        { int b = d4b.y >> 8; int p = atomicAdd(&lcur[b], 1); sbuf[p] = s4.y | ((d4b.y & 255) << 17); sbkt[p] = (unsigned short)b; }
        { int b = d4b.z >> 8; int p = atomicAdd(&lcur[b], 1); sbuf[p] = s4.z | ((d4b.z & 255) << 17); sbkt[p] = (unsigned short)b; }
        { int b = d4b.w >> 8; int p = atomicAdd(&lcur[b], 1); sbuf[p] = s4.w | ((d4b.w & 255) << 17); sbkt[p] = (unsigned short)b; }
    }
    __syncthreads();
    // pass 3: coalesced run write-out (addr = b*cap + dg[b] + j)
    for (int j = tid; j < ecnt; j += 1024) {
        int b = sbkt[j];
        unsigned idx = (unsigned)(dg[b] + j);
        if (idx < (unsigned)cap)
            packed[(size_t)b * cap + idx] = (unsigned)sbuf[j];
    }
}

// grid = 2*NB: exact per-node CSR via LDS counting sort (R6-proven body)
__global__ __launch_bounds__(1024)
void csr_sort(const unsigned* __restrict__ packed_c, const int* __restrict__ cnt_c,
              int* __restrict__ csr_c, int* __restrict__ offs_c,
              int* __restrict__ deg_c, float* __restrict__ inv_c,
              const unsigned* __restrict__ packed_d, const int* __restrict__ cnt_d,
              int* __restrict__ csr_d, int* __restrict__ offs_d,
              int* __restrict__ deg_d, float* __restrict__ inv_d) {
    __shared__ int h[256];
    __shared__ int loff[256];
    __shared__ int ws[4];
    __shared__ int ebuf[CAPC];
    int blk = blockIdx.x;
    const unsigned* packed; const int* cnt; int cap, b;
    int* csr; int* offs; int* deg; float* inv;
    if (blk < NB) { packed = packed_c; cnt = cnt_c; cap = CAPC; b = blk;
                    csr = csr_c; offs = offs_c; deg = deg_c; inv = inv_c; }
    else          { packed = packed_d; cnt = cnt_d; cap = CAPD; b = blk - NB;
                    csr = csr_d; offs = offs_d; deg = deg_d; inv = inv_d; }
    int tid = threadIdx.x;
    size_t ebeg = (size_t)b * cap;
    int ecnt = min(cnt[b], cap);
    int node0 = b << 8;
    int nn = min(256, NN - node0);
    if (tid < 256) h[tid] = 0;
    __syncthreads();
    for (int e = tid; e < ecnt; e += 1024)
        atomicAdd(&h[packed[ebeg + e] >> 17], 1);
    __syncthreads();
    int v = (tid < 256) ? h[tid] : 0;
    {
        int lane = tid & 63, w = tid >> 6;
        int xx = v;
        #pragma unroll
        for (int sh = 1; sh < 64; sh <<= 1) { int y = __shfl_up(xx, sh); if (lane >= sh) xx += y; }
        if (lane == 63 && w < 4) ws[w] = xx;
        __syncthreads();
        if (tid < 256) {
            int wb = 0;
            #pragma unroll
            for (int j = 0; j < 4; ++j) if (j < w) wb += ws[j];
            int excl = wb + xx - v;
            loff[tid] = excl;
            if (tid < nn) {
                int node = node0 + tid;
                offs[node] = (int)ebeg + excl;
                deg[node]  = v;
                inv[node]  = 1.0f / (float)(v > 1 ? v : 1);
            }
        }
    }
    __syncthreads();
    for (int e = tid; e < ecnt; e += 1024) {
        unsigned u = packed[ebeg + e];
        int p = atomicAdd(&loff[u >> 17], 1);
        ebuf[p] = (int)(u & 0x1FFFF);
    }
    __syncthreads();
    for (int e = tid; e < ecnt; e += 1024) csr[ebeg + e] = ebuf[e];
}

// ---------------- fused SAGE layer v7 (proven 73.5us/eic layer; FROZEN) ------
// At the per-CU random-request wall (~7 cyc/line, 25k req/CU/layer). R2
// (deeper MLP) and R8 (LDS src-tiling) both regressed; do not touch.
#define ACC8(RV, M) do { \
    float2 q0 = __half22float2(*(const __half2*)&RV.x); \
    float2 q1 = __half22float2(*(const __half2*)&RV.y); \
    float2 q2 = __half22float2(*(const __half2*)&RV.z); \
    float2 q3 = __half22float2(*(const __half2*)&RV.w); \
    a0 = fmaf(q0.x, M, a0); a1 = fmaf(q0.y, M, a1); \
    a2 = fmaf(q1.x, M, a2); a3 = fmaf(q1.y, M, a3); \
    a4 = fmaf(q2.x, M, a4); a5 = fmaf(q2.y, M, a5); \
    a6 = fmaf(q3.x, M, a6); a7 = fmaf(q3.y, M, a7); \
} while (0)

template<bool APPLY_BN>
__global__ __launch_bounds__(256)
void sage_layer8(const float* __restrict__ hin,       // f32 rows (self-term)
                 const __half* __restrict__ hin16,    // fp16 rows (gather)
                 const float* __restrict__ stats_in,  // [k*16]=sum, [(8+k)*16]=sumsq
                 const float* __restrict__ gin, const float* __restrict__ bin,
                 const int* __restrict__ offs, const int* __restrict__ deg,
                 const int* __restrict__ csr, const float* __restrict__ inv,
                 const float* __restrict__ Wl, const float* __restrict__ Wr,
                 float* __restrict__ hout, __half* __restrict__ hout16,
                 float* __restrict__ stats_out) {
    __shared__ float bl[16];
    int tid = threadIdx.x;
    if (tid < 16) bl[tid] = 0.f;
    __syncthreads();
    int wave = tid >> 6, lane = tid & 63, g = lane >> 3, f = lane & 7;

    float wls[8], wrs[8];
    float Bl = 0.f, Br = 0.f;
    #pragma unroll
    for (int k = 0; k < 8; ++k) {
        float w_l = Wl[f * 8 + k], w_r = Wr[f * 8 + k];
        float sck = 1.f, shk = 0.f;
        if constexpr (APPLY_BN) {
            float m = stats_in[k * 16] * (1.f / NN);
            float v = stats_in[(8 + k) * 16] * (1.f / NN) - m * m;
            float is = rsqrtf(v + BN_EPS);
            sck = gin[k] * is;
            shk = bin[k] - m * sck;
        }
        wls[k] = sck * w_l;
        wrs[k] = sck * w_r;
        Bl = fmaf(shk, w_l, Bl);
        Br = fmaf(shk, w_r, Br);
    }

    float acc_r = 0.f, acc_r2 = 0.f;
    const int stride = gridDim.x * 32;            // blocks * 4 waves * 8 nodes
    for (int i0 = (blockIdx.x * 4 + wave) * 8; i0 < NN; i0 += stride) {
        int i = i0 + g;
        int ic = min(i, NN - 1);
        bool ok = (i < NN);
        int d = ok ? deg[ic] : 0;
        int o = offs[ic];
        float im = inv[ic];
        const float4* hp = (const float4*)(hin + (size_t)ic * 8);
        float4 h0 = hp[0];
        float4 h1 = hp[1];
        float a0 = 0, a1 = 0, a2 = 0, a3 = 0, a4 = 0, a5 = 0, a6 = 0, a7 = 0;
        for (int b = 0; b < d; b += 32) {         // divergent per group: exec-masked
            int e = b + f * 4;
            const int* cp = csr + o + e;          // <=31 over-read: csr +256 padded
            int c0 = cp[0], c1 = cp[1], c2 = cp[2], c3 = cp[3];
            bool k0 = (e < d), k1 = (e + 1 < d), k2 = (e + 2 < d), k3 = (e + 3 < d);
            unsigned s0 = k0 ? ((unsigned)c0 & 0x1FFFFu) : 0u;
            unsigned s1 = k1 ? ((unsigned)c1 & 0x1FFFFu) : 0u;
            unsigned s2 = k2 ? ((unsigned)c2 & 0x1FFFFu) : 0u;
            unsigned s3 = k3 ? ((unsigned)c3 & 0x1FFFFu) : 0u;
            uint4 r0 = *(const uint4*)(hin16 + (size_t)s0 * 8);
            uint4 r1 = *(const uint4*)(hin16 + (size_t)s1 * 8);
            uint4 r2 = *(const uint4*)(hin16 + (size_t)s2 * 8);
            uint4 r3 = *(const uint4*)(hin16 + (size_t)s3 * 8);
            float m0 = k0 ? 1.f : 0.f;
            float m1 = k1 ? 1.f : 0.f;
            float m2 = k2 ? 1.f : 0.f;
            float m3 = k3 ? 1.f : 0.f;
            ACC8(r0, m0);
            ACC8(r1, m1);
            ACC8(r2, m2);
            ACC8(r3, m3);
        }
        #pragma unroll
        for (int msk = 1; msk < 8; msk <<= 1) {
            a0 += __shfl_xor(a0, msk); a1 += __shfl_xor(a1, msk);
            a2 += __shfl_xor(a2, msk); a3 += __shfl_xor(a3, msk);
            a4 += __shfl_xor(a4, msk); a5 += __shfl_xor(a5, msk);
            a6 += __shfl_xor(a6, msk); a7 += __shfl_xor(a7, msk);
        }
        float dnz = (d > 0) ? 1.f : 0.f;
        float hk[8] = { h0.x, h0.y, h0.z, h0.w, h1.x, h1.y, h1.z, h1.w };
        float ac[8] = { a0, a1, a2, a3, a4, a5, a6, a7 };
        float y = fmaf(dnz, Bl, Br);
        #pragma unroll
        for (int k = 0; k < 8; ++k) {
            y = fmaf(ac[k] * im, wls[k], y);
            y = fmaf(hk[k], wrs[k], y);
        }
        float n2 = y * y;
        n2 += __shfl_xor(n2, 1);
        n2 += __shfl_xor(n2, 2);
        n2 += __shfl_xor(n2, 4);
        float z = y / fmaxf(sqrtf(n2), 1e-12f);
        float r = fmaxf(z, 0.f);
        r = ok ? r : 0.f;
        if (ok) {
            hout[(size_t)i * 8 + f] = r;
            hout16[(size_t)i * 8 + f] = __float2half(r);
        }
        acc_r += r;
        acc_r2 += r * r;
    }
    atomicAdd(&bl[f], acc_r);
    atomicAdd(&bl[8 + f], acc_r2);
    __syncthreads();
    if (tid < 16) atomicAdd(&stats_out[tid * 16], bl[tid]);
}

__global__ void apply_bn_out(const float* __restrict__ hin,
                             const float* __restrict__ stats,
                             const float* __restrict__ g, const float* __restrict__ b,
                             float* __restrict__ out) {
    int t = blockIdx.x * blockDim.x + threadIdx.x;
    if (t >= NN * 8) return;
    int f = t & 7;
    float m = stats[f * 16] * (1.0f / NN);
    float v = stats[(8 + f) * 16] * (1.0f / NN) - m * m;
    float sc = g[f] * rsqrtf(v + BN_EPS);
    float sh = b[f] - m * sc;
    out[t] = fmaf(hin[t], sc, sh);
}

// ---------------- launch ----------------

static inline char* bump(char*& p, size_t bytes) {
    char* r = p;
    p += (bytes + 255) & ~(size_t)255;
    return r;
}

extern "C" void kernel_launch(void* const* d_in, const int* in_sizes, int n_in,
                              void* d_out, int out_size, void* d_ws, size_t ws_size,
                              hipStream_t stream) {
    const float* x   = (const float*)d_in[0];
    const int* eic   = (const int*)d_in[1];
    const int* eid   = (const int*)d_in[2];
    const float* W1l = (const float*)d_in[3];
    const float* W1r = (const float*)d_in[4];
    const float* W2l = (const float*)d_in[5];
    const float* W2r = (const float*)d_in[6];
    const float* W3l = (const float*)d_in[7];
    const float* W3r = (const float*)d_in[8];
    const float* W4l = (const float*)d_in[9];
    const float* W4r = (const float*)d_in[10];
    const float* g1 = (const float*)d_in[11];
    const float* b1 = (const float*)d_in[12];
    const float* g2 = (const float*)d_in[13];
    const float* b2 = (const float*)d_in[14];
    const float* g3 = (const float*)d_in[15];
    const float* b3 = (const float*)d_in[16];
    const float* g4 = (const float*)d_in[17];
    const float* b4 = (const float*)d_in[18];
    float* out = (float*)d_out;

    char* p = (char*)d_ws;
    float* stats   = (float*)bump(p, 5 * 256 * 4);
    int*   cnt_c   = (int*)  bump(p, NB * 4);
    int*   cnt_d   = (int*)  bump(p, NB * 4);
    int*   offs_c  = (int*)  bump(p, NN * 4);
    int*   deg_c   = (int*)  bump(p, NN * 4);
    float* inv_c   = (float*)bump(p, NN * 4);
    int*   offs_d  = (int*)  bump(p, NN * 4);
    int*   deg_d   = (int*)  bump(p, NN * 4);
    float* inv_d   = (float*)bump(p, NN * 4);
    int*   csr_c   = (int*)  bump(p, ((size_t)NB * CAPC + 256) * 4);
    int*   csr_d   = (int*)  bump(p, ((size_t)NB * CAPD + 256) * 4);
    float* xp32    = (float*)bump(p, (size_t)NN * 8 * 4);
    __half* xp16   = (__half*)bump(p, (size_t)NN * 8 * 2);
    float* W1lp    = (float*)bump(p, 64 * 4);
    float* W1rp    = (float*)bump(p, 64 * 4);
    unsigned* packed_d = (unsigned*)bump(p, (size_t)NB * CAPD * 4);
    // packed_c dead after csr_sort; overlay activation ping-pong (f32 + fp16)
    char* pc = p;
    unsigned* packed_c = (unsigned*)bump(p, (size_t)NB * CAPC * 4);
    char* pr = pc;
    float*  r_a   = (float*) bump(pr, (size_t)NN * 8 * 4);
    float*  r_b   = (float*) bump(pr, (size_t)NN * 8 * 4);
    __half* h16_a = (__half*)bump(pr, (size_t)NN * 8 * 2);
    __half* h16_b = (__half*)bump(pr, (size_t)NN * 8 * 2);
    (void)ws_size; (void)in_sizes; (void)n_in; (void)out_size;

    // 9 dispatches total
    zero_small<<<1, 1024, 0, stream>>>(cnt_c, cnt_d, stats);
    scatter_fused<<<NBK_C + NBK_D + PREPB, 1024, 0, stream>>>(
        eic, eid, cnt_c, cnt_d, packed_c, packed_d,
        x, W1l, W1r, xp32, xp16, W1lp, W1rp);
    csr_sort<<<2 * NB, 1024, 0, stream>>>(
        packed_c, cnt_c, csr_c, offs_c, deg_c, inv_c,
        packed_d, cnt_d, csr_d, offs_d, deg_d, inv_d);

    const int LB = 2048;   // v7 grid: 8192 waves, grid-stride
    sage_layer8<false><<<LB, 256, 0, stream>>>(
        xp32, xp16, nullptr, nullptr, nullptr,
        offs_c, deg_c, csr_c, inv_c, W1lp, W1rp, r_a, h16_a, stats + 0);
    sage_layer8<true><<<LB, 256, 0, stream>>>(
        r_a, h16_a, stats + 0, g1, b1,
        offs_c, deg_c, csr_c, inv_c, W4l, W4r, r_b, h16_b, stats + 256);
    sage_layer8<true><<<LB, 256, 0, stream>>>(
        r_b, h16_b, stats + 256, g2, b2,
        offs_d, deg_d, csr_d, inv_d, W2l, W2r, r_a, h16_a, stats + 512);
    sage_layer8<true><<<LB, 256, 0, stream>>>(
        r_a, h16_a, stats + 512, g3, b3,
        offs_c, deg_c, csr_c, inv_c, W3l, W3r, r_b, h16_b, stats + 768);
    sage_layer8<true><<<LB, 256, 0, stream>>>(
        r_b, h16_b, stats + 768, g4, b4,
        offs_c, deg_c, csr_c, inv_c, W3l, W3r, r_a, h16_a, stats + 1024);
    apply_bn_out<<<(NN * 8 + 255) / 256, 256, 0, stream>>>(r_a, stats + 1024, g4, b4, out);
}